// Round 1
// baseline (26.018 us; speedup 1.0000x reference)
//
#include <hip/hip_runtime.h>

#define NPATCH 196
#define NTHREADS 256

// ---- 16-amplitude real statevector helpers (wire w <-> bit (3-w), MSB-first) ----

__device__ __forceinline__ void encode4(float s[16], float a0, float a1, float a2, float a3) {
    float sn0 = __sinf(a0 * 0.5f), cs0 = __cosf(a0 * 0.5f);
    float sn1 = __sinf(a1 * 0.5f), cs1 = __cosf(a1 * 0.5f);
    float sn2 = __sinf(a2 * 0.5f), cs2 = __cosf(a2 * 0.5f);
    float sn3 = __sinf(a3 * 0.5f), cs3 = __cosf(a3 * 0.5f);
    #pragma unroll
    for (int i = 0; i < 16; ++i) {
        float v = ((i & 8) ? sn0 : cs0);
        v *= ((i & 4) ? sn1 : cs1);
        v *= ((i & 2) ? sn2 : cs2);
        v *= ((i & 1) ? sn3 : cs3);
        s[i] = v;
    }
}

template <int WIRE>
__device__ __forceinline__ void apply_ry(float s[16], float c, float sn) {
    constexpr int MASK = 1 << (3 - WIRE);
    #pragma unroll
    for (int i = 0; i < 16; ++i) {
        if (!(i & MASK)) {
            const int j = i | MASK;
            float t0 = s[i], t1 = s[j];
            s[i] = c * t0 - sn * t1;
            s[j] = sn * t0 + c * t1;
        }
    }
}

// CX: s_new[i] = s_old[i ^ TMASK] when (i & CMASK) -> swap pairs (register rename, free)
template <int CMASK, int TMASK>
__device__ __forceinline__ void apply_cx(float s[16]) {
    #pragma unroll
    for (int i = 0; i < 16; ++i) {
        if ((i & CMASK) && !(i & TMASK)) {
            const int j = i | TMASK;
            float t = s[i]; s[i] = s[j]; s[j] = t;
        }
    }
}

__global__ __launch_bounds__(NTHREADS) void quanv_fused(
    const float* __restrict__ x, const float* __restrict__ rl,
    const float* __restrict__ W, const float* __restrict__ bias,
    float* __restrict__ out)
{
    __shared__ float xs[784];
    __shared__ float feats_s[NPATCH * 4];
    __shared__ float attn_s[NPATCH];
    __shared__ float redw[4];      // cross-wave reduction scratch
    __shared__ float red_s[4][10]; // per-wave partial logits
    __shared__ float logits_s[10];

    const int b = blockIdx.x;
    const int t = threadIdx.x;
    const int lane = t & 63;
    const int wave = t >> 6;

    // ---- Phase A: image -> LDS (coalesced) ----
    const float* xb = x + (size_t)b * 784;
    for (int e = t; e < 784; e += NTHREADS) xs[e] = xb[e];
    __syncthreads();

    // ---- Phase B: per-patch statevector sim, all in registers ----
    float raw = -1e30f;
    if (t < NPATCH) {
        const int pi = t / 14;
        const int pj = t - pi * 14;
        const int base = (2 * pi) * 28 + 2 * pj;
        const float a0 = xs[base], a1 = xs[base + 1];
        const float a2 = xs[base + 28], a3 = xs[base + 29];

        float s[16];
        encode4(s, a0, a1, a2, a3);

        float rc[5], rs[5];
        #pragma unroll
        for (int k = 0; k < 5; ++k) {
            const float h = rl[k] * 0.5f;
            rs[k] = __sinf(h);
            rc[k] = __cosf(h);
        }

        apply_ry<0>(s, rc[0], rs[0]);
        apply_ry<1>(s, rc[1], rs[1]);
        apply_cx<8, 2>(s);            // CX(0,2)
        apply_ry<2>(s, rc[2], rs[2]);
        apply_ry<3>(s, rc[3], rs[3]);
        apply_cx<4, 1>(s);            // CX(1,3)
        apply_ry<0>(s, rc[4], rs[4]);
        apply_cx<2, 1>(s);            // CX(2,3)

        float f0 = 0.f, f1 = 0.f, f2 = 0.f, f3 = 0.f;
        #pragma unroll
        for (int i = 0; i < 16; ++i) {
            const float q = s[i] * s[i];
            f0 += (i & 8) ? -q : q;
            f1 += (i & 4) ? -q : q;
            f2 += (i & 2) ? -q : q;
            f3 += (i & 1) ? -q : q;
        }
        feats_s[t * 4 + 0] = f0;
        feats_s[t * 4 + 1] = f1;
        feats_s[t * 4 + 2] = f2;
        feats_s[t * 4 + 3] = f3;

        // attention circuit: re-encode feats, CX(0,1) CX(1,2) CX(2,3), measure Z0
        encode4(s, f0, f1, f2, f3);
        apply_cx<8, 4>(s);
        apply_cx<4, 2>(s);
        apply_cx<2, 1>(s);
        float r = 0.f;
        #pragma unroll
        for (int i = 0; i < 16; ++i) {
            const float q = s[i] * s[i];
            r += (i & 8) ? -q : q;
        }
        raw = r;
    }

    // ---- Phase C: softmax over 196 raw values (tree reductions) ----
    // block max
    float v = raw;
    #pragma unroll
    for (int off = 32; off > 0; off >>= 1) v = fmaxf(v, __shfl_xor(v, off));
    if (lane == 0) redw[wave] = v;
    __syncthreads();
    const float m = fmaxf(fmaxf(redw[0], redw[1]), fmaxf(redw[2], redw[3]));
    __syncthreads();

    float e = (t < NPATCH) ? __expf(raw - m) : 0.f;
    if (t < NPATCH) attn_s[t] = e;
    // block sum
    float sv = e;
    #pragma unroll
    for (int off = 32; off > 0; off >>= 1) sv += __shfl_xor(sv, off);
    if (lane == 0) redw[wave] = sv;
    __syncthreads();
    const float denom = redw[0] + redw[1] + redw[2] + redw[3];
    const float inv = 1.0f / denom;

    // ---- Phase D: logits[k] = sum_e feats[e]*attn[e/4]*inv * W[k,e] + b[k] ----
    float acc[10];
    #pragma unroll
    for (int k = 0; k < 10; ++k) acc[k] = 0.f;
    for (int ei = t; ei < 784; ei += NTHREADS) {
        const float wv = feats_s[ei] * attn_s[ei >> 2] * inv;
        #pragma unroll
        for (int k = 0; k < 10; ++k) acc[k] += wv * W[k * 784 + ei];
    }
    #pragma unroll
    for (int k = 0; k < 10; ++k) {
        #pragma unroll
        for (int off = 32; off > 0; off >>= 1) acc[k] += __shfl_xor(acc[k], off);
    }
    if (lane == 0) {
        #pragma unroll
        for (int k = 0; k < 10; ++k) red_s[wave][k] = acc[k];
    }
    __syncthreads();
    if (t < 10) {
        logits_s[t] = red_s[0][t] + red_s[1][t] + red_s[2][t] + red_s[3][t] + bias[t];
    }
    __syncthreads();

    // ---- Phase E: log_softmax over 10 classes ----
    if (t < 10) {
        float m2 = logits_s[0];
        #pragma unroll
        for (int k = 1; k < 10; ++k) m2 = fmaxf(m2, logits_s[k]);
        float ssum = 0.f;
        #pragma unroll
        for (int k = 0; k < 10; ++k) ssum += __expf(logits_s[k] - m2);
        out[b * 10 + t] = logits_s[t] - (m2 + __logf(ssum));
    }
}

extern "C" void kernel_launch(void* const* d_in, const int* in_sizes, int n_in,
                              void* d_out, int out_size, void* d_ws, size_t ws_size,
                              hipStream_t stream) {
    const float* x    = (const float*)d_in[0];
    const float* rl   = (const float*)d_in[1];
    const float* W    = (const float*)d_in[2];
    const float* bias = (const float*)d_in[3];
    float* out = (float*)d_out;
    const int B = in_sizes[0] / 784;
    quanv_fused<<<B, NTHREADS, 0, stream>>>(x, rl, W, bias, out);
}

// Round 2
// 20.247 us; speedup vs baseline: 1.2850x; 1.2850x over previous
//
#include <hip/hip_runtime.h>

#define NPATCH 196
#define NTHREADS 256

// Closed-form quanvolution (derived in Heisenberg picture; wire w <-> bit 3-w):
//   alpha = a0+rl0, beta = a1+rl1
//   f1 = cos(beta)
//   f0 = cos(rl4)cos(alpha) - sin(rl4)sin(alpha)sin(a2)
//   f2 = cos(rl2)cos(alpha)cos(a2) - sin(rl2)sin(a2)
//   f3 = f1 * cos(a3+rl3) * f2
//   attn raw = cos(f0)   (CX chain never flips wire-0 bit -> Z0 invariant;
//                         product state => <Z0> = cos(angle0))

__global__ __launch_bounds__(NTHREADS) void quanv_fused(
    const float* __restrict__ x, const float* __restrict__ rl,
    const float* __restrict__ W, const float* __restrict__ bias,
    float* __restrict__ out)
{
    __shared__ float xs[784];
    __shared__ float rltrig[4];      // cos rl2, sin rl2, cos rl4, sin rl4
    __shared__ float redw[4];        // cross-wave softmax-denominator scratch
    __shared__ float red_s[4][10];   // per-wave partial logits
    __shared__ float logits_s[10];

    const int b = blockIdx.x;
    const int t = threadIdx.x;
    const int lane = t & 63;
    const int wave = t >> 6;

    // uniform scalar loads (compiler emits s_load: rl index is constant)
    const float rl0 = rl[0], rl1 = rl[1], rl3v = rl[3];

    // ---- Phase A: image -> LDS (float4 coalesced), stage uniform trig ----
    if (t < NPATCH) {
        reinterpret_cast<float4*>(xs)[t] =
            reinterpret_cast<const float4*>(x + (size_t)b * 784)[t];
    }
    if (t == 0) { float s, c; __sincosf(rl[2], &s, &c); rltrig[0] = c; rltrig[1] = s; }
    if (t == 1) { float s, c; __sincosf(rl[4], &s, &c); rltrig[2] = c; rltrig[3] = s; }
    __syncthreads();

    // ---- Phase B: closed-form per-patch features ----
    float f0 = 0.f, f1 = 0.f, f2 = 0.f, f3 = 0.f, e = 0.f;
    if (t < NPATCH) {
        const float crl2 = rltrig[0], srl2 = rltrig[1];
        const float crl4 = rltrig[2], srl4 = rltrig[3];
        const int pi = t / 14;
        const int pj = t - pi * 14;
        const int base = (2 * pi) * 28 + 2 * pj;
        const float a0 = xs[base], a1 = xs[base + 1];
        const float a2 = xs[base + 28], a3 = xs[base + 29];

        float sa, ca; __sincosf(a0 + rl0, &sa, &ca);
        float s2, c2; __sincosf(a2, &s2, &c2);
        f1 = __cosf(a1 + rl1);
        const float cd = __cosf(a3 + rl3v);
        f0 = crl4 * ca - srl4 * sa * s2;
        f2 = crl2 * ca * c2 - srl2 * s2;
        f3 = f1 * cd * f2;

        // attention raw = cos(f0); raw in [-1,1] -> softmax max-pass unnecessary
        e = __expf(__cosf(f0));
    }

    // ---- Phase C: softmax denominator (single block reduction) ----
    float sv = e;
    #pragma unroll
    for (int off = 32; off > 0; off >>= 1) sv += __shfl_xor(sv, off);
    if (lane == 0) redw[wave] = sv;
    __syncthreads();
    const float inv = 1.0f / (redw[0] + redw[1] + redw[2] + redw[3]);

    // ---- Phase D: partial logits; thread t owns patch t's float4 chunk ----
    float acc[10];
    #pragma unroll
    for (int k = 0; k < 10; ++k) acc[k] = 0.f;
    if (t < NPATCH) {
        const float sc = e * inv;
        const float w0 = f0 * sc, w1 = f1 * sc, w2 = f2 * sc, w3 = f3 * sc;
        const float4* __restrict__ Wv4 = reinterpret_cast<const float4*>(W);
        #pragma unroll
        for (int k = 0; k < 10; ++k) {
            const float4 wk = Wv4[k * NPATCH + t];
            acc[k] = w0 * wk.x + w1 * wk.y + w2 * wk.z + w3 * wk.w;
        }
    }
    #pragma unroll
    for (int k = 0; k < 10; ++k) {
        #pragma unroll
        for (int off = 32; off > 0; off >>= 1) acc[k] += __shfl_xor(acc[k], off);
    }
    if (lane == 0) {
        #pragma unroll
        for (int k = 0; k < 10; ++k) red_s[wave][k] = acc[k];
    }
    __syncthreads();
    if (t < 10) {
        logits_s[t] = red_s[0][t] + red_s[1][t] + red_s[2][t] + red_s[3][t] + bias[t];
    }
    __syncthreads();

    // ---- Phase E: log_softmax over 10 classes ----
    if (t < 10) {
        float m2 = logits_s[0];
        #pragma unroll
        for (int k = 1; k < 10; ++k) m2 = fmaxf(m2, logits_s[k]);
        float ssum = 0.f;
        #pragma unroll
        for (int k = 0; k < 10; ++k) ssum += __expf(logits_s[k] - m2);
        out[b * 10 + t] = logits_s[t] - (m2 + __logf(ssum));
    }
}

extern "C" void kernel_launch(void* const* d_in, const int* in_sizes, int n_in,
                              void* d_out, int out_size, void* d_ws, size_t ws_size,
                              hipStream_t stream) {
    const float* x    = (const float*)d_in[0];
    const float* rl   = (const float*)d_in[1];
    const float* W    = (const float*)d_in[2];
    const float* bias = (const float*)d_in[3];
    float* out = (float*)d_out;
    const int B = in_sizes[0] / 784;
    quanv_fused<<<B, NTHREADS, 0, stream>>>(x, rl, W, bias, out);
}

// Round 3
// 13.443 us; speedup vs baseline: 1.9355x; 1.5062x over previous
//
#include <hip/hip_runtime.h>

#define NTHREADS 256   // 4 waves; each wave owns one image
#define NPATCH 196

// Closed-form quanvolution (Heisenberg picture; wire w <-> bit 3-w):
//   alpha = a0+rl0
//   f1 = cos(a1+rl1)
//   f0 = cos(rl4)cos(alpha) - sin(rl4)sin(alpha)sin(a2)
//   f2 = cos(rl2)cos(alpha)cos(a2) - sin(rl2)sin(a2)
//   f3 = f1 * cos(a3+rl3) * f2
//   attn raw = cos(f0)  (CX chain leaves Z0 invariant; product state -> <Z0>=cos)

__device__ __forceinline__ float dot4(float4 a, float4 b) {
    return a.x * b.x + a.y * b.y + a.z * b.z + a.w * b.w;
}

__global__ __launch_bounds__(NTHREADS) void quanv_fused(
    const float* __restrict__ x, const float* __restrict__ rl,
    const float* __restrict__ W, const float* __restrict__ bias,
    float* __restrict__ out)
{
    __shared__ float xs[4][784];

    const int lane = threadIdx.x & 63;
    const int wave = threadIdx.x >> 6;
    const int img  = blockIdx.x * 4 + wave;

    // ---- stage this wave's image into its LDS segment (float4, coalesced) ----
    const float4* __restrict__ xsrc = reinterpret_cast<const float4*>(x + (size_t)img * 784);
    float4* xd = reinterpret_cast<float4*>(xs[wave]);
    #pragma unroll
    for (int r = 0; r < 3; ++r) xd[lane + 64 * r] = xsrc[lane + 64 * r];
    if (lane < 4) xd[192 + lane] = xsrc[192 + lane];
    __syncthreads();   // the only barrier

    // ---- uniform rl trig (scalar loads, cheap per-lane trans) ----
    float srl2, crl2, srl4, crl4;
    __sincosf(rl[2], &srl2, &crl2);
    __sincosf(rl[4], &srl4, &crl4);
    const float rl0 = rl[0], rl1 = rl[1], rl3v = rl[3];

    // ---- per-patch closed form; lane owns p = lane, lane+64, lane+128 (+tail) ----
    const float* xw = xs[wave];
    auto patchf = [&](int p, float& f0, float& f1, float& f2, float& f3) {
        const int pi = p / 14;
        const int base = 56 * pi + 2 * (p - pi * 14);
        const float2 top = *reinterpret_cast<const float2*>(&xw[base]);
        const float2 bot = *reinterpret_cast<const float2*>(&xw[base + 28]);
        float sa, ca; __sincosf(top.x + rl0, &sa, &ca);
        float s2, c2; __sincosf(bot.x, &s2, &c2);
        f1 = __cosf(top.y + rl1);
        const float cd = __cosf(bot.y + rl3v);
        f0 = crl4 * ca - srl4 * sa * s2;
        f2 = crl2 * ca * c2 - srl2 * s2;
        f3 = f1 * cd * f2;
    };

    const int p0 = lane, p1 = lane + 64, p2 = lane + 128, p3 = 192 + lane;
    const bool has4 = (lane < 4);

    float f00, f01, f02, f03; patchf(p0, f00, f01, f02, f03);
    float f10, f11, f12, f13; patchf(p1, f10, f11, f12, f13);
    float f20, f21, f22, f23; patchf(p2, f20, f21, f22, f23);
    float f30, f31, f32, f33; patchf(has4 ? p3 : p0, f30, f31, f32, f33);

    const float e0 = __expf(__cosf(f00));
    const float e1 = __expf(__cosf(f10));
    const float e2 = __expf(__cosf(f20));
    const float e3 = has4 ? __expf(__cosf(f30)) : 0.f;

    // ---- softmax denominator: wave shuffle reduce (raw in [-1,1], no max pass) ----
    float sv = e0 + e1 + e2 + e3;
    #pragma unroll
    for (int off = 32; off > 0; off >>= 1) sv += __shfl_xor(sv, off);
    const float inv = 1.0f / sv;

    const float sc0 = e0 * inv, sc1 = e1 * inv, sc2 = e2 * inv, sc3 = e3 * inv;
    const float4 g0 = make_float4(f00 * sc0, f01 * sc0, f02 * sc0, f03 * sc0);
    const float4 g1 = make_float4(f10 * sc1, f11 * sc1, f12 * sc1, f13 * sc1);
    const float4 g2 = make_float4(f20 * sc2, f21 * sc2, f22 * sc2, f23 * sc2);
    const float4 g3 = make_float4(f30 * sc3, f31 * sc3, f32 * sc3, f33 * sc3);

    // ---- partial logits: coalesced float4 W reads, L1/L2-resident ----
    const float4* __restrict__ W4 = reinterpret_cast<const float4*>(W);
    float acc[10];
    #pragma unroll
    for (int k = 0; k < 10; ++k) {
        acc[k] = dot4(g0, W4[k * NPATCH + p0])
               + dot4(g1, W4[k * NPATCH + p1])
               + dot4(g2, W4[k * NPATCH + p2]);
    }
    if (has4) {
        #pragma unroll
        for (int k = 0; k < 10; ++k) acc[k] += dot4(g3, W4[k * NPATCH + p3]);
    }

    // ---- wave butterfly: every lane ends with all 10 logits ----
    #pragma unroll
    for (int k = 0; k < 10; ++k) {
        #pragma unroll
        for (int off = 32; off > 0; off >>= 1) acc[k] += __shfl_xor(acc[k], off);
        acc[k] += bias[k];
    }

    // ---- log_softmax over 10 (uniform per-lane work) ----
    float m2 = acc[0];
    #pragma unroll
    for (int k = 1; k < 10; ++k) m2 = fmaxf(m2, acc[k]);
    float ssum = 0.f;
    #pragma unroll
    for (int k = 0; k < 10; ++k) ssum += __expf(acc[k] - m2);
    const float lse = m2 + __logf(ssum);

    if (lane < 10) {
        float myv = acc[0];
        #pragma unroll
        for (int k = 1; k < 10; ++k) myv = (lane == k) ? acc[k] : myv;
        out[(size_t)img * 10 + lane] = myv - lse;
    }
}

extern "C" void kernel_launch(void* const* d_in, const int* in_sizes, int n_in,
                              void* d_out, int out_size, void* d_ws, size_t ws_size,
                              hipStream_t stream) {
    const float* x    = (const float*)d_in[0];
    const float* rl   = (const float*)d_in[1];
    const float* W    = (const float*)d_in[2];
    const float* bias = (const float*)d_in[3];
    float* out = (float*)d_out;
    const int B = in_sizes[0] / 784;          // 4096
    quanv_fused<<<B / 4, NTHREADS, 0, stream>>>(x, rl, W, bias, out);
}

// Round 4
// 13.116 us; speedup vs baseline: 1.9837x; 1.0249x over previous
//
#include <hip/hip_runtime.h>

#define NTHREADS 256   // 4 waves; 2 waves per image; 2 images per block
#define NPATCH 196

// Closed-form quanvolution (Heisenberg picture; wire w <-> bit 3-w):
//   alpha = a0+rl0
//   f1 = cos(a1+rl1)
//   f0 = cos(rl4)cos(alpha) - sin(rl4)sin(alpha)sin(a2)
//   f2 = cos(rl2)cos(alpha)cos(a2) - sin(rl2)sin(a2)
//   f3 = f1 * cos(a3+rl3) * f2
//   attn raw = cos(f0)  (CX chain leaves Z0 invariant; product state -> <Z0>=cos)

__device__ __forceinline__ float dot4(float4 a, float4 b) {
    return a.x * b.x + a.y * b.y + a.z * b.z + a.w * b.w;
}

// wave64 sum on the VALU pipe via DPP (6 v_add_f32_dpp); result valid in lane 63.
__device__ __forceinline__ float wave_sum63(float x) {
#define DPP_STEP(ctrl, rmask)                                                   \
    x += __int_as_float(__builtin_amdgcn_update_dpp(                            \
        0, __float_as_int(x), (ctrl), (rmask), 0xf, true));
    DPP_STEP(0x111, 0xf)   // row_shr:1
    DPP_STEP(0x112, 0xf)   // row_shr:2
    DPP_STEP(0x114, 0xf)   // row_shr:4
    DPP_STEP(0x118, 0xf)   // row_shr:8  -> lane15 of each row = row sum
    DPP_STEP(0x142, 0xa)   // row_bcast:15 into rows 1,3
    DPP_STEP(0x143, 0xc)   // row_bcast:31 into rows 2,3 -> lane63 = total
#undef DPP_STEP
    return x;
}

__global__ __launch_bounds__(NTHREADS, 6) void quanv_fused(
    const float* __restrict__ x, const float* __restrict__ rl,
    const float* __restrict__ W, const float* __restrict__ bias,
    float* __restrict__ out)
{
    __shared__ float redw[4];        // per-wave softmax partial denominators
    __shared__ float redl[4][10];    // per-wave partial logits

    const int lane = threadIdx.x & 63;
    const int wave = threadIdx.x >> 6;   // 0..3
    const int il   = wave >> 1;          // image within block (0,1)
    const int half = wave & 1;           // which 98-patch half
    const int img  = blockIdx.x * 2 + il;

    const float* __restrict__ xb = x + (size_t)img * 784;

    // ---- uniform rl trig ----
    float srl2, crl2, srl4, crl4;
    __sincosf(rl[2], &srl2, &crl2);
    __sincosf(rl[4], &srl4, &crl4);
    const float rl0 = rl[0], rl1 = rl[1], rl3v = rl[3];

    // ---- patches: p0 for all lanes, p1 for lanes < 34 (clamped otherwise) ----
    const int p0 = half * 98 + lane;
    const bool has2 = (lane < 34);
    const int pp1 = has2 ? (p0 + 64) : p0;   // clamped duplicate -> finite, weight 0

    auto patchf = [&](int p, float& f0, float& f1, float& f2, float& f3) {
        const int pi = p / 14;
        const int base = 56 * pi + 2 * (p - pi * 14);
        const float2 top = *reinterpret_cast<const float2*>(xb + base);
        const float2 bot = *reinterpret_cast<const float2*>(xb + base + 28);
        float sa, ca; __sincosf(top.x + rl0, &sa, &ca);
        float s2, c2; __sincosf(bot.x, &s2, &c2);
        f1 = __cosf(top.y + rl1);
        const float cd = __cosf(bot.y + rl3v);
        f0 = crl4 * ca - srl4 * sa * s2;
        f2 = crl2 * ca * c2 - srl2 * s2;
        f3 = f1 * cd * f2;
    };

    float f00, f01, f02, f03; patchf(p0,  f00, f01, f02, f03);
    float f10, f11, f12, f13; patchf(pp1, f10, f11, f12, f13);

    const float e0 = __expf(__cosf(f00));
    const float e1 = has2 ? __expf(__cosf(f10)) : 0.f;   // clamped patch weight = 0

    // ---- softmax denominator: DPP wave sum + tiny LDS cross-wave combine ----
    const float svw = wave_sum63(e0 + e1);
    if (lane == 63) redw[wave] = svw;
    __syncthreads();
    const float inv = 1.0f / (redw[wave & ~1] + redw[wave | 1]);

    const float sc0 = e0 * inv, sc1 = e1 * inv;          // sc1 = 0 on clamped lanes
    const float4 g0 = make_float4(f00 * sc0, f01 * sc0, f02 * sc0, f03 * sc0);
    const float4 g1 = make_float4(f10 * sc1, f11 * sc1, f12 * sc1, f13 * sc1);

    // ---- partial logits: coalesced float4 W reads (L1-resident) ----
    const float4* __restrict__ W4 = reinterpret_cast<const float4*>(W);
    float acc[10];
    #pragma unroll
    for (int k = 0; k < 10; ++k) {
        acc[k] = dot4(g0, W4[k * NPATCH + p0]) + dot4(g1, W4[k * NPATCH + pp1]);
    }

    // ---- 10 wave sums on the VALU pipe (no LDS-pipe butterfly) ----
    #pragma unroll
    for (int k = 0; k < 10; ++k) acc[k] = wave_sum63(acc[k]);
    if (lane == 63) {
        #pragma unroll
        for (int k = 0; k < 10; ++k) redl[wave][k] = acc[k];
    }
    __syncthreads();

    // ---- combine halves, log_softmax, write (half-0 wave of each image) ----
    if (half == 0) {
        float lg[10];
        #pragma unroll
        for (int k = 0; k < 10; ++k)
            lg[k] = redl[wave][k] + redl[wave + 1][k] + bias[k];
        float m2 = lg[0];
        #pragma unroll
        for (int k = 1; k < 10; ++k) m2 = fmaxf(m2, lg[k]);
        float ssum = 0.f;
        #pragma unroll
        for (int k = 0; k < 10; ++k) ssum += __expf(lg[k] - m2);
        const float lse = m2 + __logf(ssum);
        if (lane < 10) {
            float myv = lg[0];
            #pragma unroll
            for (int k = 1; k < 10; ++k) myv = (lane == k) ? lg[k] : myv;
            out[(size_t)img * 10 + lane] = myv - lse;
        }
    }
}

extern "C" void kernel_launch(void* const* d_in, const int* in_sizes, int n_in,
                              void* d_out, int out_size, void* d_ws, size_t ws_size,
                              hipStream_t stream) {
    const float* x    = (const float*)d_in[0];
    const float* rl   = (const float*)d_in[1];
    const float* W    = (const float*)d_in[2];
    const float* bias = (const float*)d_in[3];
    float* out = (float*)d_out;
    const int B = in_sizes[0] / 784;          // 4096
    quanv_fused<<<B / 2, NTHREADS, 0, stream>>>(x, rl, W, bias, out);
}

// Round 5
// 12.185 us; speedup vs baseline: 2.1353x; 1.0764x over previous
//
#include <hip/hip_runtime.h>

#define NPATCH 196

// Closed-form quanvolution (Heisenberg picture; wire w <-> bit 3-w):
//   alpha = a0+rl0
//   f1 = cos(a1+rl1)
//   f0 = cos(rl4)cos(alpha) - sin(rl4)sin(alpha)sin(a2)
//   f2 = cos(rl2)cos(alpha)cos(a2) - sin(rl2)sin(a2)
//   f3 = f1 * cos(a3+rl3) * f2
//   attn raw = cos(f0)  (CX chain leaves Z0 invariant; product state -> <Z0>=cos)
// One wave per image, zero barriers, zero LDS. Lane q owns patch pair (2q,2q+1)
// whose 2x4 pixel block is two contiguous float4s.

__device__ __forceinline__ float dot4(float4 a, float4 b) {
    return a.x * b.x + a.y * b.y + a.z * b.z + a.w * b.w;
}

// wave64 sum on the VALU pipe via DPP; total lands in lane 63, broadcast via readlane.
__device__ __forceinline__ float wave_sum_bcast(float x) {
#define DPP_STEP(ctrl, rmask)                                                   \
    x += __int_as_float(__builtin_amdgcn_update_dpp(                            \
        0, __float_as_int(x), (ctrl), (rmask), 0xf, true));
    DPP_STEP(0x111, 0xf)   // row_shr:1
    DPP_STEP(0x112, 0xf)   // row_shr:2
    DPP_STEP(0x114, 0xf)   // row_shr:4
    DPP_STEP(0x118, 0xf)   // row_shr:8  -> lane15 of each 16-row = row sum
    DPP_STEP(0x142, 0xa)   // row_bcast:15 into rows 1,3
    DPP_STEP(0x143, 0xc)   // row_bcast:31 into rows 2,3 -> lane63 = total
#undef DPP_STEP
    return __int_as_float(__builtin_amdgcn_readlane(__float_as_int(x), 63));
}

__global__ __launch_bounds__(256) void quanv_fused(
    const float* __restrict__ x, const float* __restrict__ rl,
    const float* __restrict__ W, const float* __restrict__ bias,
    float* __restrict__ out)
{
    const int lane = threadIdx.x & 63;
    const int wave = threadIdx.x >> 6;           // 4 fully independent waves
    const int img  = blockIdx.x * 4 + wave;

    const float* __restrict__ xb = x + (size_t)img * 784;

    // uniform rl trig
    float srl2, crl2, srl4, crl4;
    __sincosf(rl[2], &srl2, &crl2);
    __sincosf(rl[4], &srl4, &crl4);
    const float rl0 = rl[0], rl1 = rl[1], rl3v = rl[3];

    // per-pair closed form: pair q = patches (2q, 2q+1), pixels = 2 contiguous float4
    auto pairf = [&](int q, float4& fA, float4& fB, float& eA, float& eB) {
        const int r = (2 * q) / 14;              // patch row
        const int c = (2 * q) - r * 14;          // even patch col
        const float4 top = *reinterpret_cast<const float4*>(xb + 56 * r + 2 * c);
        const float4 bot = *reinterpret_cast<const float4*>(xb + 56 * r + 2 * c + 28);
        // patch A
        {
            float sa, ca; __sincosf(top.x + rl0, &sa, &ca);
            float s2, c2; __sincosf(bot.x, &s2, &c2);
            const float f1 = __cosf(top.y + rl1);
            const float cd = __cosf(bot.y + rl3v);
            const float f0 = crl4 * ca - srl4 * sa * s2;
            const float f2 = crl2 * ca * c2 - srl2 * s2;
            fA = make_float4(f0, f1, f2, f1 * cd * f2);
            eA = __expf(__cosf(f0));
        }
        // patch B
        {
            float sa, ca; __sincosf(top.z + rl0, &sa, &ca);
            float s2, c2; __sincosf(bot.z, &s2, &c2);
            const float f1 = __cosf(top.w + rl1);
            const float cd = __cosf(bot.w + rl3v);
            const float f0 = crl4 * ca - srl4 * sa * s2;
            const float f2 = crl2 * ca * c2 - srl2 * s2;
            fB = make_float4(f0, f1, f2, f1 * cd * f2);
            eB = __expf(__cosf(f0));
        }
    };

    // 98 pairs: all lanes take pair `lane`; lanes 0..33 also take pair lane+64
    const bool has2 = (lane < 34);
    const int q2 = has2 ? (lane + 64) : lane;    // clamped duplicate (finite, weight 0)

    float4 fA0, fB0, fA1, fB1;
    float eA0, eB0, eA1, eB1;
    pairf(lane, fA0, fB0, eA0, eB0);
    pairf(q2,   fA1, fB1, eA1, eB1);
    if (!has2) { eA1 = 0.f; eB1 = 0.f; }

    // softmax denominator (raw = cos(f0) in [-1,1] -> no max pass needed)
    const float inv = 1.0f / wave_sum_bcast(eA0 + eB0 + eA1 + eB1);

    const float wA0 = eA0 * inv, wB0 = eB0 * inv;
    const float wA1 = eA1 * inv, wB1 = eB1 * inv;   // 0 on clamped lanes
    const float4 gA0 = make_float4(fA0.x * wA0, fA0.y * wA0, fA0.z * wA0, fA0.w * wA0);
    const float4 gB0 = make_float4(fB0.x * wB0, fB0.y * wB0, fB0.z * wB0, fB0.w * wB0);
    const float4 gA1 = make_float4(fA1.x * wA1, fA1.y * wA1, fA1.z * wA1, fA1.w * wA1);
    const float4 gB1 = make_float4(fB1.x * wB1, fB1.y * wB1, fB1.z * wB1, fB1.w * wB1);

    // partial logits: W columns for pair q are two contiguous float4s (L1-hot)
    const float4* __restrict__ W4 = reinterpret_cast<const float4*>(W);
    float acc[10];
    #pragma unroll
    for (int k = 0; k < 10; ++k) {
        const int kb = k * NPATCH;
        acc[k] = dot4(gA0, W4[kb + 2 * lane])
               + dot4(gB0, W4[kb + 2 * lane + 1])
               + dot4(gA1, W4[kb + 2 * q2])
               + dot4(gB1, W4[kb + 2 * q2 + 1]);
    }

    // 10 wave reductions -> uniform logits
    float lg[10];
    #pragma unroll
    for (int k = 0; k < 10; ++k) lg[k] = wave_sum_bcast(acc[k]) + bias[k];

    // log_softmax over 10 (uniform per-lane)
    float m2 = lg[0];
    #pragma unroll
    for (int k = 1; k < 10; ++k) m2 = fmaxf(m2, lg[k]);
    float ssum = 0.f;
    #pragma unroll
    for (int k = 0; k < 10; ++k) ssum += __expf(lg[k] - m2);
    const float lse = m2 + __logf(ssum);

    if (lane < 10) {
        float myv = lg[0];
        #pragma unroll
        for (int k = 1; k < 10; ++k) myv = (lane == k) ? lg[k] : myv;
        out[(size_t)img * 10 + lane] = myv - lse;
    }
}

extern "C" void kernel_launch(void* const* d_in, const int* in_sizes, int n_in,
                              void* d_out, int out_size, void* d_ws, size_t ws_size,
                              hipStream_t stream) {
    const float* x    = (const float*)d_in[0];
    const float* rl   = (const float*)d_in[1];
    const float* W    = (const float*)d_in[2];
    const float* bias = (const float*)d_in[3];
    float* out = (float*)d_out;
    const int B = in_sizes[0] / 784;          // 4096
    quanv_fused<<<B / 4, 256, 0, stream>>>(x, rl, W, bias, out);
}

// Round 6
// 11.570 us; speedup vs baseline: 2.2488x; 1.0532x over previous
//
#include <hip/hip_runtime.h>

#define NPATCH 196

// Closed-form quanvolution (Heisenberg picture; wire w <-> bit 3-w):
//   alpha = a0+rl0
//   f1 = cos(a1+rl1)
//   f0 = cos(rl4)cos(alpha) - sin(rl4)sin(alpha)sin(a2)
//   f2 = cos(rl2)cos(alpha)cos(a2) - sin(rl2)sin(a2)
//   f3 = f1 * cos(a3+rl3) * f2
//   attn raw = cos(f0)  (CX chain leaves Z0 invariant; product state -> <Z0>=cos)
// TWO images per wave: W float4 loads are shared by both images' dot products,
// halving per-image L1 W traffic. Zero barriers, zero LDS.

__device__ __forceinline__ float dot4(float4 a, float4 b) {
    return a.x * b.x + a.y * b.y + a.z * b.z + a.w * b.w;
}

// wave64 sum on the VALU pipe via DPP; total lands in lane 63, broadcast via readlane.
__device__ __forceinline__ float wave_sum_bcast(float x) {
#define DPP_STEP(ctrl, rmask)                                                   \
    x += __int_as_float(__builtin_amdgcn_update_dpp(                            \
        0, __float_as_int(x), (ctrl), (rmask), 0xf, true));
    DPP_STEP(0x111, 0xf)   // row_shr:1
    DPP_STEP(0x112, 0xf)   // row_shr:2
    DPP_STEP(0x114, 0xf)   // row_shr:4
    DPP_STEP(0x118, 0xf)   // row_shr:8  -> lane15 of each 16-row = row sum
    DPP_STEP(0x142, 0xa)   // row_bcast:15 into rows 1,3
    DPP_STEP(0x143, 0xc)   // row_bcast:31 into rows 2,3 -> lane63 = total
#undef DPP_STEP
    return __int_as_float(__builtin_amdgcn_readlane(__float_as_int(x), 63));
}

__global__ __launch_bounds__(256) void quanv_fused(
    const float* __restrict__ x, const float* __restrict__ rl,
    const float* __restrict__ W, const float* __restrict__ bias,
    float* __restrict__ out)
{
    const int lane = threadIdx.x & 63;
    const int wave = threadIdx.x >> 6;              // 4 independent waves
    const int imgA = blockIdx.x * 8 + 2 * wave;     // wave owns images imgA, imgA+1
    const int imgB = imgA + 1;

    const float* __restrict__ xa = x + (size_t)imgA * 784;
    const float* __restrict__ xbp = x + (size_t)imgB * 784;

    // uniform rl trig
    float srl2, crl2, srl4, crl4;
    __sincosf(rl[2], &srl2, &crl2);
    __sincosf(rl[4], &srl4, &crl4);
    const float rl0 = rl[0], rl1 = rl[1], rl3v = rl[3];

    // per-pair closed form: pair q = patches (2q, 2q+1), pixels = 2 contiguous float4
    auto pairf = [&](const float* __restrict__ xb, int q,
                     float4& fA, float4& fB, float& eA, float& eB) {
        const int r = (2 * q) / 14;
        const int c = (2 * q) - r * 14;
        const float4 top = *reinterpret_cast<const float4*>(xb + 56 * r + 2 * c);
        const float4 bot = *reinterpret_cast<const float4*>(xb + 56 * r + 2 * c + 28);
        {
            float sa, ca; __sincosf(top.x + rl0, &sa, &ca);
            float s2, c2; __sincosf(bot.x, &s2, &c2);
            const float f1 = __cosf(top.y + rl1);
            const float cd = __cosf(bot.y + rl3v);
            const float f0 = crl4 * ca - srl4 * sa * s2;
            const float f2 = crl2 * ca * c2 - srl2 * s2;
            fA = make_float4(f0, f1, f2, f1 * cd * f2);
            eA = __expf(__cosf(f0));
        }
        {
            float sa, ca; __sincosf(top.z + rl0, &sa, &ca);
            float s2, c2; __sincosf(bot.z, &s2, &c2);
            const float f1 = __cosf(top.w + rl1);
            const float cd = __cosf(bot.w + rl3v);
            const float f0 = crl4 * ca - srl4 * sa * s2;
            const float f2 = crl2 * ca * c2 - srl2 * s2;
            fB = make_float4(f0, f1, f2, f1 * cd * f2);
            eB = __expf(__cosf(f0));
        }
    };

    // 98 pairs: all lanes take pair `lane`; lanes 0..33 also take pair lane+64
    const bool has2 = (lane < 34);
    const int q2 = has2 ? (lane + 64) : lane;       // clamped duplicate (weight 0)

    // image A
    float4 aA0, aB0, aA1, aB1; float eaA0, eaB0, eaA1, eaB1;
    pairf(xa, lane, aA0, aB0, eaA0, eaB0);
    pairf(xa, q2,   aA1, aB1, eaA1, eaB1);
    if (!has2) { eaA1 = 0.f; eaB1 = 0.f; }
    // image B
    float4 bA0, bB0, bA1, bB1; float ebA0, ebB0, ebA1, ebB1;
    pairf(xbp, lane, bA0, bB0, ebA0, ebB0);
    pairf(xbp, q2,   bA1, bB1, ebA1, ebB1);
    if (!has2) { ebA1 = 0.f; ebB1 = 0.f; }

    // softmax denominators (raw = cos(f0) in [-1,1] -> no max pass)
    const float invA = 1.0f / wave_sum_bcast(eaA0 + eaB0 + eaA1 + eaB1);
    const float invB = 1.0f / wave_sum_bcast(ebA0 + ebB0 + ebA1 + ebB1);

    auto scale4 = [](float4 f, float w) {
        return make_float4(f.x * w, f.y * w, f.z * w, f.w * w);
    };
    const float4 gA0 = scale4(aA0, eaA0 * invA), gB0 = scale4(aB0, eaB0 * invA);
    const float4 gA1 = scale4(aA1, eaA1 * invA), gB1 = scale4(aB1, eaB1 * invA);
    const float4 hA0 = scale4(bA0, ebA0 * invB), hB0 = scale4(bB0, ebB0 * invB);
    const float4 hA1 = scale4(bA1, ebA1 * invB), hB1 = scale4(bB1, ebB1 * invB);

    // partial logits: W float4s loaded ONCE, used for both images
    const float4* __restrict__ W4 = reinterpret_cast<const float4*>(W);
    float accA[10], accB[10];
    #pragma unroll
    for (int k = 0; k < 10; ++k) {
        const int kb = k * NPATCH;
        const float4 w0 = W4[kb + 2 * lane];
        const float4 w1 = W4[kb + 2 * lane + 1];
        const float4 w2 = W4[kb + 2 * q2];
        const float4 w3 = W4[kb + 2 * q2 + 1];
        accA[k] = dot4(gA0, w0) + dot4(gB0, w1) + dot4(gA1, w2) + dot4(gB1, w3);
        accB[k] = dot4(hA0, w0) + dot4(hB0, w1) + dot4(hA1, w2) + dot4(hB1, w3);
    }

    // 20 wave reductions -> uniform logits for both images
    float lgA[10], lgB[10];
    #pragma unroll
    for (int k = 0; k < 10; ++k) {
        const float bk = bias[k];
        lgA[k] = wave_sum_bcast(accA[k]) + bk;
        lgB[k] = wave_sum_bcast(accB[k]) + bk;
    }

    // log_softmax over 10 (uniform per-lane), both images
    float mA = lgA[0], mB = lgB[0];
    #pragma unroll
    for (int k = 1; k < 10; ++k) { mA = fmaxf(mA, lgA[k]); mB = fmaxf(mB, lgB[k]); }
    float sA = 0.f, sB = 0.f;
    #pragma unroll
    for (int k = 0; k < 10; ++k) { sA += __expf(lgA[k] - mA); sB += __expf(lgB[k] - mB); }
    const float lseA = mA + __logf(sA);
    const float lseB = mB + __logf(sB);

    if (lane < 10) {
        float vA = lgA[0], vB = lgB[0];
        #pragma unroll
        for (int k = 1; k < 10; ++k) {
            vA = (lane == k) ? lgA[k] : vA;
            vB = (lane == k) ? lgB[k] : vB;
        }
        out[(size_t)imgA * 10 + lane] = vA - lseA;
        out[(size_t)imgB * 10 + lane] = vB - lseB;
    }
}

extern "C" void kernel_launch(void* const* d_in, const int* in_sizes, int n_in,
                              void* d_out, int out_size, void* d_ws, size_t ws_size,
                              hipStream_t stream) {
    const float* x    = (const float*)d_in[0];
    const float* rl   = (const float*)d_in[1];
    const float* W    = (const float*)d_in[2];
    const float* bias = (const float*)d_in[3];
    float* out = (float*)d_out;
    const int B = in_sizes[0] / 784;          // 4096
    quanv_fused<<<B / 8, 256, 0, stream>>>(x, rl, W, bias, out);
}